// Round 1
// baseline (9.636 us; speedup 1.0000x reference)
//
#include <hip/hip_runtime.h>

// DifferentiableShockProximity: B=64, nx=2048, fp32.
// Per batch row:
//   shock[i] for interface i in [1, nx-1]: uses state[i-1], state[i]
//   min_dist[j] = dx * min over shock i of |(j+0.5) - i|
//   out[j] = exp(-min_dist / 0.05), 0 if no shock in the row.
// Separable via prefix-max (nearest shock to the left) and suffix-min
// (nearest shock to the right) of shock interface indices.

#define NX 2048
#define THREADS 256            // 8 cells per thread
#define NEG_SENT (-1.0e9f)
#define POS_SENT ( 1.0e9f)

__global__ __launch_bounds__(THREADS)
void shock_proximity_kernel(const float* __restrict__ state,
                            const float* __restrict__ dx_ptr,
                            float* __restrict__ out)
{
    const int b = blockIdx.x;
    const int t = threadIdx.x;
    const float dx = dx_ptr[0];
    const float* row = state + (size_t)b * NX;

    // --- load 8 contiguous cells + left neighbor ---
    const int base = t * 8;
    float4 lo = *reinterpret_cast<const float4*>(row + base);
    float4 hi = *reinterpret_cast<const float4*>(row + base + 4);
    float v[8] = {lo.x, lo.y, lo.z, lo.w, hi.x, hi.y, hi.z, hi.w};
    float prev = (t > 0) ? row[base - 1] : 0.0f;

    // --- shock mask for the 8 interfaces this thread owns (i = base+m) ---
    // EXACT numpy fp32 op order: charL = 1-2*rL; s = (1-rL)-rR; charR = 1-2*rR
    float A[8];   // i if shock else -inf   (for prefix max)
    float Bv[8];  // i if shock else +inf   (for suffix min)
    #pragma unroll
    for (int m = 0; m < 8; ++m) {
        const int i = base + m;
        const float rL = (m == 0) ? prev : v[m - 1];
        const float rR = v[m];
        const float charL = 1.0f - 2.0f * rL;
        const float charR = 1.0f - 2.0f * rR;
        const float s     = (1.0f - rL) - rR;
        const bool shock  = (i >= 1) && (charL > s) && (s > charR);
        A[m]  = shock ? (float)i : NEG_SENT;
        Bv[m] = shock ? (float)i : POS_SENT;
    }

    // --- local inclusive prefix max / exclusive suffix min ---
    float P[8], S[8];
    P[0] = A[0];
    #pragma unroll
    for (int m = 1; m < 8; ++m) P[m] = fmaxf(P[m - 1], A[m]);
    S[7] = POS_SENT;
    #pragma unroll
    for (int m = 6; m >= 0; --m) S[m] = fminf(S[m + 1], Bv[m + 1]);
    const float maxAll = P[7];
    const float minAll = fminf(S[0], Bv[0]);

    const int lane = t & 63;
    const int wave = t >> 6;

    // --- wave-level inclusive prefix max of thread aggregates ---
    float incMax = maxAll;
    #pragma unroll
    for (int d = 1; d < 64; d <<= 1) {
        float y = __shfl_up(incMax, d);
        if (lane >= d) incMax = fmaxf(incMax, y);
    }
    float exclMax = __shfl_up(incMax, 1);
    if (lane == 0) exclMax = NEG_SENT;

    // --- wave-level inclusive suffix min of thread aggregates ---
    float incMin = minAll;
    #pragma unroll
    for (int d = 1; d < 64; d <<= 1) {
        float y = __shfl_down(incMin, d);
        if (lane + d < 64) incMin = fminf(incMin, y);
    }
    float exclMin = __shfl_down(incMin, 1);
    if (lane == 63) exclMin = POS_SENT;

    // --- cross-wave combine (4 waves) ---
    __shared__ float wTotMax[4];
    __shared__ float wTotMin[4];
    if (lane == 63) wTotMax[wave] = incMax;  // full-wave max
    if (lane == 0)  wTotMin[wave] = incMin;  // full-wave min
    __syncthreads();
    float offL = exclMax;
    for (int w = 0; w < wave; ++w)     offL = fmaxf(offL, wTotMax[w]);
    float offR = exclMin;
    for (int w = wave + 1; w < 4; ++w) offR = fminf(offR, wTotMin[w]);

    // --- distances + exp, vectorized store ---
    float o[8];
    #pragma unroll
    for (int m = 0; m < 8; ++m) {
        const int j = base + m;
        const float Lpos = fmaxf(P[m], offL);   // nearest shock idx <= j
        const float Rpos = fminf(S[m], offR);   // nearest shock idx >= j+1
        const float cc = ((float)j + 0.5f) * dx;
        const float dL = cc - Lpos * dx;        // >= 0 for real shocks
        const float dR = Rpos * dx - cc;        // >= 0 for real shocks
        const float d  = fminf(dL, dR);
        o[m] = expf(-d / 0.05f);                // sentinel -> exp(-~1e7) = 0
    }
    float4 o0 = make_float4(o[0], o[1], o[2], o[3]);
    float4 o1 = make_float4(o[4], o[5], o[6], o[7]);
    *reinterpret_cast<float4*>(out + (size_t)b * NX + base)     = o0;
    *reinterpret_cast<float4*>(out + (size_t)b * NX + base + 4) = o1;
}

extern "C" void kernel_launch(void* const* d_in, const int* in_sizes, int n_in,
                              void* d_out, int out_size, void* d_ws, size_t ws_size,
                              hipStream_t stream) {
    const float* state = (const float*)d_in[0];
    const float* dx    = (const float*)d_in[1];
    float* out = (float*)d_out;
    const int B = in_sizes[0] / NX;   // 64
    shock_proximity_kernel<<<B, THREADS, 0, stream>>>(state, dx, out);
}